// Round 1
// baseline (12530.205 us; speedup 1.0000x reference)
//
#include <hip/hip_runtime.h>

#define NN 100000
#define NE 1600000
#define DF 32
#define KIT 5
#define MU 0.01f

__device__ __forceinline__ void atomicMaxPosF32(float* addr, float v) {
    // valid for non-negative floats (IEEE positive floats order like ints)
    atomicMax((int*)addr, __float_as_int(v));
}

__global__ void init_max_kernel(float* __restrict__ maxn) {
    if (threadIdx.x < 8) maxn[threadIdx.x] = 0.0f;
}

__global__ __launch_bounds__(256) void copy_kernel(float4* __restrict__ dst,
                                                   const float4* __restrict__ src) {
    int i = blockIdx.x * blockDim.x + threadIdx.x;
    if (i < NN * DF / 4) dst[i] = src[i];
}

// One 32-lane group per edge: compute ||h[row]-h[col]||, store, track global max.
__global__ __launch_bounds__(256) void norm_kernel(const float* __restrict__ h,
                                                   const int* __restrict__ row,
                                                   const int* __restrict__ col,
                                                   float* __restrict__ norms,
                                                   float* __restrict__ maxslot) {
    const int lane = threadIdx.x & 31;
    const int e = (blockIdx.x * blockDim.x + threadIdx.x) >> 5;
    float nrm = 0.0f;
    if (e < NE) {
        const int r = row[e];
        const int c = col[e];
        const float d = h[r * DF + lane] - h[c * DF + lane];
        float s = d * d;
        // sum across the 32-lane group
        #pragma unroll
        for (int m = 16; m > 0; m >>= 1) s += __shfl_xor(s, m, 32);
        nrm = fmaxf(sqrtf(s), 1e-6f);
        if (lane == 0) norms[e] = nrm;
    }
    // block-level max reduction (values are group-uniform already)
    float m = fmaxf(nrm, __shfl_xor(nrm, 32, 64));  // wave max (2 groups/wave)
    __shared__ float smax[4];
    const int wave = threadIdx.x >> 6;
    if ((threadIdx.x & 63) == 0) smax[wave] = m;
    __syncthreads();
    if (threadIdx.x == 0) {
        float bm = fmaxf(fmaxf(smax[0], smax[1]), fmaxf(smax[2], smax[3]));
        atomicMaxPosF32(maxslot, bm);
    }
}

// One 32-lane group per edge: w = sqrt(max/norm); hn[row] += -MU*w*(h[col]-h[row])
__global__ __launch_bounds__(256) void scatter_kernel(const float* __restrict__ h,
                                                      const int* __restrict__ row,
                                                      const int* __restrict__ col,
                                                      const float* __restrict__ norms,
                                                      const float* __restrict__ maxslot,
                                                      float* __restrict__ hn) {
    const int lane = threadIdx.x & 31;
    const int e = (blockIdx.x * blockDim.x + threadIdx.x) >> 5;
    if (e >= NE) return;
    const int r = row[e];
    const int c = col[e];
    const float nrm = norms[e];
    const float mx = *maxslot;
    const float w = sqrtf(mx / nrm);  // (nrm/mx)^(P-2), P=1.5
    const float hr = h[r * DF + lane];
    const float hc = h[c * DF + lane];
    const float msg = -MU * w * (hc - hr);
    atomicAdd(&hn[r * DF + lane], msg);
}

extern "C" void kernel_launch(void* const* d_in, const int* in_sizes, int n_in,
                              void* d_out, int out_size, void* d_ws, size_t ws_size,
                              hipStream_t stream) {
    const float* h_in = (const float*)d_in[0];
    const int* row = (const int*)d_in[1];
    const int* col = row + NE;
    float* out = (float*)d_out;

    float* norms = (float*)d_ws;        // NE floats
    float* maxn = norms + NE;           // 8 floats (one slot per iteration)
    float* hA = maxn + 8;               // NN*DF floats

    init_max_kernel<<<1, 64, 0, stream>>>(maxn);

    // ping-pong: in -> out -> hA -> out -> hA -> out
    const float* cur[KIT] = {h_in, out, hA, out, hA};
    float* nxt[KIT] = {out, hA, out, hA, out};

    const int edge_blocks = (NE * 32) / 256;         // 200000
    const int copy_blocks = (NN * DF / 4 + 255) / 256;

    for (int it = 0; it < KIT; ++it) {
        norm_kernel<<<edge_blocks, 256, 0, stream>>>(cur[it], row, col, norms, maxn + it);
        copy_kernel<<<copy_blocks, 256, 0, stream>>>((float4*)nxt[it], (const float4*)cur[it]);
        scatter_kernel<<<edge_blocks, 256, 0, stream>>>(cur[it], row, col, norms, maxn + it,
                                                        nxt[it]);
    }
}

// Round 2
// 2315.916 us; speedup vs baseline: 5.4105x; 5.4105x over previous
//
#include <hip/hip_runtime.h>

#define NN 100000
#define NE 1600000
#define DF 32
#define KIT 5
#define MU 0.01f
#define NSLOT 1024

__global__ __launch_bounds__(256) void copy_kernel(float4* __restrict__ dst,
                                                   const float4* __restrict__ src) {
    int i = blockIdx.x * blockDim.x + threadIdx.x;
    if (i < NN * DF / 4) dst[i] = src[i];
}

// One 32-lane group per edge: compute ||h[row]-h[col]||, store norm, and
// track max via per-wave shuffle reduce + spread atomics (no shared/barrier,
// no single-address contention).
__global__ __launch_bounds__(256) void norm_kernel(const float* __restrict__ h,
                                                   const int* __restrict__ row,
                                                   const int* __restrict__ col,
                                                   float* __restrict__ norms,
                                                   int* __restrict__ maxslots) {
    const int lane = threadIdx.x & 31;
    const int e = (blockIdx.x * blockDim.x + threadIdx.x) >> 5;
    float nrm = 0.0f;
    if (e < NE) {
        const int r = row[e];
        const int c = col[e];
        const float d = h[r * DF + lane] - h[c * DF + lane];
        float s = d * d;
        #pragma unroll
        for (int m = 16; m > 0; m >>= 1) s += __shfl_xor(s, m, 32);
        nrm = fmaxf(sqrtf(s), 1e-6f);
        if (lane == 0) norms[e] = nrm;
    }
    // wave-level max (two 32-groups per wave)
    float m = fmaxf(nrm, __shfl_xor(nrm, 32, 64));
    if ((threadIdx.x & 63) == 0) {
        // positive floats order like ints; 0xAA poison is negative -> harmless
        atomicMax(&maxslots[blockIdx.x & (NSLOT - 1)], __float_as_int(m));
    }
}

// 1024 slots -> single float max
__global__ __launch_bounds__(1024) void reduce_max_kernel(const int* __restrict__ slots,
                                                          float* __restrict__ maxout) {
    int v = slots[threadIdx.x];
    #pragma unroll
    for (int m = 32; m > 0; m >>= 1) v = max(v, __shfl_xor(v, m, 64));
    __shared__ int sm[16];
    const int wave = threadIdx.x >> 6;
    if ((threadIdx.x & 63) == 0) sm[wave] = v;
    __syncthreads();
    if (threadIdx.x == 0) {
        int bm = sm[0];
        #pragma unroll
        for (int i = 1; i < 16; ++i) bm = max(bm, sm[i]);
        *maxout = __int_as_float(bm);
    }
}

// One 32-lane group per edge: w = sqrt(max/norm); hn[row] += -MU*w*(h[col]-h[row])
__global__ __launch_bounds__(256) void scatter_kernel(const float* __restrict__ h,
                                                      const int* __restrict__ row,
                                                      const int* __restrict__ col,
                                                      const float* __restrict__ norms,
                                                      const float* __restrict__ maxslot,
                                                      float* __restrict__ hn) {
    const int lane = threadIdx.x & 31;
    const int e = (blockIdx.x * blockDim.x + threadIdx.x) >> 5;
    if (e >= NE) return;
    const int r = row[e];
    const int c = col[e];
    const float nrm = norms[e];
    const float mx = *maxslot;
    const float w = sqrtf(mx / nrm);  // (nrm/mx)^(P-2), P=1.5
    const float hr = h[r * DF + lane];
    const float hc = h[c * DF + lane];
    const float msg = -MU * w * (hc - hr);
    atomicAdd(&hn[r * DF + lane], msg);
}

extern "C" void kernel_launch(void* const* d_in, const int* in_sizes, int n_in,
                              void* d_out, int out_size, void* d_ws, size_t ws_size,
                              hipStream_t stream) {
    const float* h_in = (const float*)d_in[0];
    const int* row = (const int*)d_in[1];
    const int* col = row + NE;
    float* out = (float*)d_out;

    float* norms = (float*)d_ws;             // NE floats
    float* maxn = norms + NE;                // KIT floats (final max per iter)
    int* maxslots = (int*)(maxn + KIT);      // KIT * NSLOT ints
    float* hA = (float*)(maxslots + KIT * NSLOT);  // NN*DF floats

    // ping-pong: in -> out -> hA -> out -> hA -> out
    const float* cur[KIT] = {h_in, out, hA, out, hA};
    float* nxt[KIT] = {out, hA, out, hA, out};

    const int edge_blocks = (NE * 32) / 256;  // 200000
    const int copy_blocks = (NN * DF / 4 + 255) / 256;

    for (int it = 0; it < KIT; ++it) {
        norm_kernel<<<edge_blocks, 256, 0, stream>>>(cur[it], row, col, norms,
                                                     maxslots + it * NSLOT);
        reduce_max_kernel<<<1, 1024, 0, stream>>>(maxslots + it * NSLOT, maxn + it);
        copy_kernel<<<copy_blocks, 256, 0, stream>>>((float4*)nxt[it], (const float4*)cur[it]);
        scatter_kernel<<<edge_blocks, 256, 0, stream>>>(cur[it], row, col, norms, maxn + it,
                                                        nxt[it]);
    }
}

// Round 3
// 2105.325 us; speedup vs baseline: 5.9517x; 1.1000x over previous
//
#include <hip/hip_runtime.h>

#define NN 100000
#define NE 1600000
#define DF 32
#define KIT 5
#define MU 0.01f
#define NSLOT 1024
#define NV4 (NN * DF / 4)   // 800000 float4 elements in h / S

__global__ __launch_bounds__(256) void zero_kernel(float4* __restrict__ S) {
    int i = blockIdx.x * blockDim.x + threadIdx.x;
    if (i < NV4) S[i] = make_float4(0.f, 0.f, 0.f, 0.f);
}

// One 32-lane group per edge. Gather both endpoints once, compute
// n = max(||hr-hc||,1e-6), track global max (spread atomics), and
// accumulate the UNSCALED message (hc-hr)*rsqrt(n) into S[row].
// The global-max factor sqrt(M) is applied later in update_kernel:
//   h_next = h - MU*sqrt(M)*S      (since w = (n/M)^-0.5 = sqrt(M)/sqrt(n))
__global__ __launch_bounds__(256) void edge_kernel(const float* __restrict__ h,
                                                   const int* __restrict__ row,
                                                   const int* __restrict__ col,
                                                   float* __restrict__ S,
                                                   int* __restrict__ maxslots) {
    const int lane = threadIdx.x & 31;
    const int e = (blockIdx.x * blockDim.x + threadIdx.x) >> 5;
    float n = 0.0f;
    if (e < NE) {
        const int r = row[e];
        const int c = col[e];
        const float hr = h[r * DF + lane];
        const float hc = h[c * DF + lane];
        const float d = hr - hc;
        float s = d * d;
        #pragma unroll
        for (int m = 16; m > 0; m >>= 1) s += __shfl_xor(s, m, 32);
        n = fmaxf(sqrtf(s), 1e-6f);
        const float val = (hc - hr) * rsqrtf(n);
        atomicAdd(&S[r * DF + lane], val);
    }
    // wave max (two 32-groups per wave), spread over 1024 slots
    float m2 = fmaxf(n, __shfl_xor(n, 32, 64));
    if ((threadIdx.x & 63) == 0) {
        // positive floats order like ints; 0xAA poison is negative -> loses
        atomicMax(&maxslots[blockIdx.x & (NSLOT - 1)], __float_as_int(m2));
    }
}

// h_next = h - MU*sqrt(M)*S ; also zero S for the next iteration.
// Each block redundantly reduces the 1024 max-slots (all L2-hot).
__global__ __launch_bounds__(256) void update_kernel(const float4* __restrict__ hcur,
                                                     float4* __restrict__ hnxt,
                                                     float4* __restrict__ S,
                                                     const int* __restrict__ slots) {
    const int t = threadIdx.x;
    int v = max(max(slots[t], slots[t + 256]), max(slots[t + 512], slots[t + 768]));
    #pragma unroll
    for (int m = 32; m > 0; m >>= 1) v = max(v, __shfl_xor(v, m, 64));
    __shared__ int sm[4];
    __shared__ float sscale;
    if ((t & 63) == 0) sm[t >> 6] = v;
    __syncthreads();
    if (t == 0) {
        int bm = max(max(sm[0], sm[1]), max(sm[2], sm[3]));
        sscale = MU * sqrtf(__int_as_float(bm));
    }
    __syncthreads();
    const float scale = sscale;
    const int i = blockIdx.x * blockDim.x + t;
    if (i < NV4) {
        const float4 hv = hcur[i];
        const float4 sv = S[i];
        float4 o;
        o.x = hv.x - scale * sv.x;
        o.y = hv.y - scale * sv.y;
        o.z = hv.z - scale * sv.z;
        o.w = hv.w - scale * sv.w;
        hnxt[i] = o;
        S[i] = make_float4(0.f, 0.f, 0.f, 0.f);
    }
}

extern "C" void kernel_launch(void* const* d_in, const int* in_sizes, int n_in,
                              void* d_out, int out_size, void* d_ws, size_t ws_size,
                              hipStream_t stream) {
    const float* h_in = (const float*)d_in[0];
    const int* row = (const int*)d_in[1];
    const int* col = row + NE;
    float* out = (float*)d_out;

    float* S = (float*)d_ws;                       // NN*DF floats
    int* maxslots = (int*)(S + NN * DF);           // KIT * NSLOT ints
    float* hA = (float*)(maxslots + KIT * NSLOT);  // NN*DF floats

    // ping-pong: in -> out -> hA -> out -> hA -> out
    const float* cur[KIT] = {h_in, out, hA, out, hA};
    float* nxt[KIT] = {out, hA, out, hA, out};

    const int edge_blocks = (NE * 32) / 256;       // 200000
    const int node_blocks = (NV4 + 255) / 256;     // 3125

    zero_kernel<<<node_blocks, 256, 0, stream>>>((float4*)S);

    for (int it = 0; it < KIT; ++it) {
        edge_kernel<<<edge_blocks, 256, 0, stream>>>(cur[it], row, col, S,
                                                     maxslots + it * NSLOT);
        update_kernel<<<node_blocks, 256, 0, stream>>>((const float4*)cur[it],
                                                       (float4*)nxt[it], (float4*)S,
                                                       maxslots + it * NSLOT);
    }
}

// Round 4
// 1125.529 us; speedup vs baseline: 11.1327x; 1.8705x over previous
//
#include <hip/hip_runtime.h>

#define NN 100000
#define NE 1600000
#define DF 32
#define KIT 5
#define MU 0.01f
#define NSLOT 1024
#define NV4 (NN * DF / 4)

// ---------- one-time CSR build (row is iteration-invariant) ----------

__global__ __launch_bounds__(256) void zero_deg_kernel(int* __restrict__ deg) {
    int i = blockIdx.x * blockDim.x + threadIdx.x;
    if (i < NN) deg[i] = 0;
}

__global__ __launch_bounds__(256) void hist_kernel(const int* __restrict__ row,
                                                   int* __restrict__ deg) {
    int e = blockIdx.x * blockDim.x + threadIdx.x;
    if (e < NE) atomicAdd(&deg[row[e]], 1);
}

// single-block exclusive scan of deg[NN] -> rowptr, cursor
__global__ __launch_bounds__(1024) void scan_kernel(const int* __restrict__ deg,
                                                    int* __restrict__ rowptr,
                                                    int* __restrict__ cursor) {
    const int t = threadIdx.x;
    const int CH = (NN + 1023) / 1024;  // 98
    const int base = t * CH;
    int total = 0;
    for (int i = 0; i < CH; ++i) {
        int idx = base + i;
        if (idx < NN) total += deg[idx];
    }
    __shared__ int sh[1024];
    sh[t] = total;
    __syncthreads();
    for (int off = 1; off < 1024; off <<= 1) {
        int v = (t >= off) ? sh[t - off] : 0;
        __syncthreads();
        sh[t] += v;
        __syncthreads();
    }
    int run = sh[t] - total;  // exclusive prefix
    for (int i = 0; i < CH; ++i) {
        int idx = base + i;
        if (idx < NN) {
            rowptr[idx] = run;
            cursor[idx] = run;
            run += deg[idx];
        }
    }
    if (t == 1023) rowptr[NN] = NE;
}

__global__ __launch_bounds__(256) void fill_kernel(const int* __restrict__ row,
                                                   const int* __restrict__ col,
                                                   int* __restrict__ cursor,
                                                   int* __restrict__ colsorted) {
    int e = blockIdx.x * blockDim.x + threadIdx.x;
    if (e < NE) {
        int pos = atomicAdd(&cursor[row[e]], 1);
        colsorted[pos] = col[e];
    }
}

// ---------- per-iteration ----------

// One 32-lane group per node (lane = feature dim). Loop its CSR edges:
// gather h[col], n = max(||hr-hc||,1e-6), acc += (hc-hr)*rsqrt(n).
// Plain store of S (no atomics). Global-max tracked via spread atomicMax
// (0xAA poison is a negative int -> always loses to positive floats).
__global__ __launch_bounds__(256) void agg_kernel(const float* __restrict__ h,
                                                  const int* __restrict__ rowptr,
                                                  const int* __restrict__ colsorted,
                                                  float* __restrict__ S,
                                                  int* __restrict__ maxslots) {
    const int lane = threadIdx.x & 31;
    const int node = (blockIdx.x * blockDim.x + threadIdx.x) >> 5;
    float nmax = 0.0f;
    if (node < NN) {
        const float hr = h[node * DF + lane];
        const int start = rowptr[node];
        const int end = rowptr[node + 1];
        float acc = 0.0f;
        // software pipeline: prefetch next col's feature while reducing current
        float hc_next = 0.0f;
        if (start < end) hc_next = h[colsorted[start] * DF + lane];
        for (int k = start; k < end; ++k) {
            const float hc = hc_next;
            if (k + 1 < end) hc_next = h[colsorted[k + 1] * DF + lane];
            const float d = hr - hc;
            float s = d * d;
            #pragma unroll
            for (int m = 16; m > 0; m >>= 1) s += __shfl_xor(s, m, 32);
            const float n = fmaxf(sqrtf(s), 1e-6f);
            nmax = fmaxf(nmax, n);
            acc += (hc - hr) * rsqrtf(n);
        }
        S[node * DF + lane] = acc;
    }
    float m2 = fmaxf(nmax, __shfl_xor(nmax, 32, 64));
    if ((threadIdx.x & 63) == 0) {
        atomicMax(&maxslots[blockIdx.x & (NSLOT - 1)], __float_as_int(m2));
    }
}

// h_out = h_in - MU*sqrt(M)*S   (elementwise; in-place safe)
__global__ __launch_bounds__(256) void update_kernel(const float4* __restrict__ hcur,
                                                     float4* __restrict__ hnxt,
                                                     const float4* __restrict__ S,
                                                     const int* __restrict__ slots) {
    const int t = threadIdx.x;
    int v = max(max(slots[t], slots[t + 256]), max(slots[t + 512], slots[t + 768]));
    #pragma unroll
    for (int m = 32; m > 0; m >>= 1) v = max(v, __shfl_xor(v, m, 64));
    __shared__ int sm[4];
    __shared__ float sscale;
    if ((t & 63) == 0) sm[t >> 6] = v;
    __syncthreads();
    if (t == 0) {
        int bm = max(max(sm[0], sm[1]), max(sm[2], sm[3]));
        sscale = MU * sqrtf(__int_as_float(bm));
    }
    __syncthreads();
    const float scale = sscale;
    const int i = blockIdx.x * blockDim.x + t;
    if (i < NV4) {
        const float4 hv = hcur[i];
        const float4 sv = S[i];
        float4 o;
        o.x = hv.x - scale * sv.x;
        o.y = hv.y - scale * sv.y;
        o.z = hv.z - scale * sv.z;
        o.w = hv.w - scale * sv.w;
        hnxt[i] = o;
    }
}

extern "C" void kernel_launch(void* const* d_in, const int* in_sizes, int n_in,
                              void* d_out, int out_size, void* d_ws, size_t ws_size,
                              hipStream_t stream) {
    const float* h_in = (const float*)d_in[0];
    const int* row = (const int*)d_in[1];
    const int* col = row + NE;
    float* out = (float*)d_out;

    float* S = (float*)d_ws;                        // NN*DF f32
    int* maxslots = (int*)(S + NN * DF);            // KIT*NSLOT
    int* deg = maxslots + KIT * NSLOT;              // NN
    int* rowptr = deg + NN;                         // NN+1
    int* cursor = rowptr + NN + 1;                  // NN
    int* colsorted = cursor + NN;                   // NE

    const int eb = (NE + 255) / 256;
    const int nb = (NN + 255) / 256;
    const int gb = (NN * 32 + 255) / 256;           // 12500
    const int ub = (NV4 + 255) / 256;               // 3125

    zero_deg_kernel<<<nb, 256, 0, stream>>>(deg);
    hist_kernel<<<eb, 256, 0, stream>>>(row, deg);
    scan_kernel<<<1, 1024, 0, stream>>>(deg, rowptr, cursor);
    fill_kernel<<<eb, 256, 0, stream>>>(row, col, cursor, colsorted);

    for (int it = 0; it < KIT; ++it) {
        const float* cur = (it == 0) ? h_in : out;
        agg_kernel<<<gb, 256, 0, stream>>>(cur, rowptr, colsorted, S,
                                           maxslots + it * NSLOT);
        update_kernel<<<ub, 256, 0, stream>>>((const float4*)cur, (float4*)out,
                                              (const float4*)S,
                                              maxslots + it * NSLOT);
    }
}

// Round 5
// 670.672 us; speedup vs baseline: 18.6831x; 1.6782x over previous
//
#include <hip/hip_runtime.h>

#define NN 100000
#define NE 1600000
#define DF 32
#define KIT 5
#define MU 0.01f
#define NSLOT 1024
#define NV4 (NN * DF / 4)

#define SCAN_CHUNK 1024                      // elements per block in the scan
#define SCAN_NB ((NN + SCAN_CHUNK - 1) / SCAN_CHUNK)  // 98 blocks

// ---------- one-time CSR build (row is iteration-invariant) ----------

__global__ __launch_bounds__(256) void zero_deg_kernel(int* __restrict__ deg) {
    int i = blockIdx.x * blockDim.x + threadIdx.x;
    if (i < NN) deg[i] = 0;
}

__global__ __launch_bounds__(256) void hist_kernel(const int* __restrict__ row,
                                                   int* __restrict__ deg) {
    int e = blockIdx.x * blockDim.x + threadIdx.x;
    if (e < NE) atomicAdd(&deg[row[e]], 1);
}

// stage 1: per-block sums of 1024-element chunks
__global__ __launch_bounds__(256) void blocksum_kernel(const int* __restrict__ deg,
                                                       int* __restrict__ bsum) {
    const int t = threadIdx.x;
    const int base = blockIdx.x * SCAN_CHUNK + t * 4;
    int s = 0;
    #pragma unroll
    for (int i = 0; i < 4; ++i) {
        int idx = base + i;
        if (idx < NN) s += deg[idx];
    }
    #pragma unroll
    for (int m = 32; m > 0; m >>= 1) s += __shfl_xor(s, m, 64);
    __shared__ int sm[4];
    if ((t & 63) == 0) sm[t >> 6] = s;
    __syncthreads();
    if (t == 0) bsum[blockIdx.x] = sm[0] + sm[1] + sm[2] + sm[3];
}

// stage 2: exclusive scan of the 98 block sums (one tiny block)
__global__ __launch_bounds__(128) void scanbsum_kernel(int* __restrict__ bsum) {
    __shared__ int sh[SCAN_NB];
    const int t = threadIdx.x;
    if (t < SCAN_NB) sh[t] = bsum[t];
    __syncthreads();
    if (t == 0) {
        int run = 0;
        for (int i = 0; i < SCAN_NB; ++i) {
            int v = sh[i];
            sh[i] = run;
            run += v;
        }
    }
    __syncthreads();
    if (t < SCAN_NB) bsum[t] = sh[t];
}

// stage 3: per-block exclusive scan + offset -> rowptr, cursor
__global__ __launch_bounds__(256) void scanfinal_kernel(const int* __restrict__ deg,
                                                        const int* __restrict__ bsum,
                                                        int* __restrict__ rowptr,
                                                        int* __restrict__ cursor) {
    const int t = threadIdx.x;
    const int base = blockIdx.x * SCAN_CHUNK + t * 4;
    int d[4];
    int s = 0;
    #pragma unroll
    for (int i = 0; i < 4; ++i) {
        int idx = base + i;
        d[i] = (idx < NN) ? deg[idx] : 0;
        s += d[i];
    }
    __shared__ int sh[256];
    sh[t] = s;
    __syncthreads();
    // Hillis-Steele over 256 thread-totals
    for (int off = 1; off < 256; off <<= 1) {
        int v = (t >= off) ? sh[t - off] : 0;
        __syncthreads();
        sh[t] += v;
        __syncthreads();
    }
    int run = bsum[blockIdx.x] + sh[t] - s;  // exclusive prefix for this thread
    #pragma unroll
    for (int i = 0; i < 4; ++i) {
        int idx = base + i;
        if (idx < NN) {
            rowptr[idx] = run;
            cursor[idx] = run;
            run += d[i];
        }
    }
    if (blockIdx.x == 0 && t == 0) rowptr[NN] = NE;
}

__global__ __launch_bounds__(256) void fill_kernel(const int* __restrict__ row,
                                                   const int* __restrict__ col,
                                                   int* __restrict__ cursor,
                                                   int* __restrict__ colsorted) {
    int e = blockIdx.x * blockDim.x + threadIdx.x;
    if (e < NE) {
        int pos = atomicAdd(&cursor[row[e]], 1);
        colsorted[pos] = col[e];
    }
}

// ---------- per-iteration ----------

// One 32-lane group per node (lane = feature dim). Unrolled by 2 edges so two
// independent shuffle-reduce chains are in flight (the per-edge critical path
// is the 6-step cross-lane reduction; 2x ILP). Plain store of S (no atomics).
__global__ __launch_bounds__(256) void agg_kernel(const float* __restrict__ h,
                                                  const int* __restrict__ rowptr,
                                                  const int* __restrict__ colsorted,
                                                  float* __restrict__ S,
                                                  int* __restrict__ maxslots) {
    const int lane = threadIdx.x & 31;
    const int node = (blockIdx.x * blockDim.x + threadIdx.x) >> 5;
    float nmax = 0.0f;
    if (node < NN) {
        const float hr = h[node * DF + lane];
        const int start = rowptr[node];
        const int end = rowptr[node + 1];
        float acc = 0.0f;
        int k = start;
        for (; k + 1 < end; k += 2) {
            const int c0 = colsorted[k];
            const int c1 = colsorted[k + 1];
            const float hc0 = h[c0 * DF + lane];
            const float hc1 = h[c1 * DF + lane];
            const float d0 = hr - hc0;
            const float d1 = hr - hc1;
            float s0 = d0 * d0;
            float s1 = d1 * d1;
            #pragma unroll
            for (int m = 16; m > 0; m >>= 1) {
                s0 += __shfl_xor(s0, m, 32);
                s1 += __shfl_xor(s1, m, 32);
            }
            const float n0 = fmaxf(sqrtf(s0), 1e-6f);
            const float n1 = fmaxf(sqrtf(s1), 1e-6f);
            nmax = fmaxf(nmax, fmaxf(n0, n1));
            acc += (hc0 - hr) * rsqrtf(n0) + (hc1 - hr) * rsqrtf(n1);
        }
        if (k < end) {
            const int c0 = colsorted[k];
            const float hc0 = h[c0 * DF + lane];
            const float d0 = hr - hc0;
            float s0 = d0 * d0;
            #pragma unroll
            for (int m = 16; m > 0; m >>= 1) s0 += __shfl_xor(s0, m, 32);
            const float n0 = fmaxf(sqrtf(s0), 1e-6f);
            nmax = fmaxf(nmax, n0);
            acc += (hc0 - hr) * rsqrtf(n0);
        }
        S[node * DF + lane] = acc;
    }
    float m2 = fmaxf(nmax, __shfl_xor(nmax, 32, 64));
    if ((threadIdx.x & 63) == 0) {
        // positive floats order like ints; 0xAA poison is negative -> loses
        atomicMax(&maxslots[blockIdx.x & (NSLOT - 1)], __float_as_int(m2));
    }
}

// h_out = h_in - MU*sqrt(M)*S   (elementwise; in-place safe)
__global__ __launch_bounds__(256) void update_kernel(const float4* __restrict__ hcur,
                                                     float4* __restrict__ hnxt,
                                                     const float4* __restrict__ S,
                                                     const int* __restrict__ slots) {
    const int t = threadIdx.x;
    int v = max(max(slots[t], slots[t + 256]), max(slots[t + 512], slots[t + 768]));
    #pragma unroll
    for (int m = 32; m > 0; m >>= 1) v = max(v, __shfl_xor(v, m, 64));
    __shared__ int sm[4];
    __shared__ float sscale;
    if ((t & 63) == 0) sm[t >> 6] = v;
    __syncthreads();
    if (t == 0) {
        int bm = max(max(sm[0], sm[1]), max(sm[2], sm[3]));
        sscale = MU * sqrtf(__int_as_float(bm));
    }
    __syncthreads();
    const float scale = sscale;
    const int i = blockIdx.x * blockDim.x + t;
    if (i < NV4) {
        const float4 hv = hcur[i];
        const float4 sv = S[i];
        float4 o;
        o.x = hv.x - scale * sv.x;
        o.y = hv.y - scale * sv.y;
        o.z = hv.z - scale * sv.z;
        o.w = hv.w - scale * sv.w;
        hnxt[i] = o;
    }
}

extern "C" void kernel_launch(void* const* d_in, const int* in_sizes, int n_in,
                              void* d_out, int out_size, void* d_ws, size_t ws_size,
                              hipStream_t stream) {
    const float* h_in = (const float*)d_in[0];
    const int* row = (const int*)d_in[1];
    const int* col = row + NE;
    float* out = (float*)d_out;

    float* S = (float*)d_ws;                        // NN*DF f32
    int* maxslots = (int*)(S + NN * DF);            // KIT*NSLOT
    int* deg = maxslots + KIT * NSLOT;              // NN
    int* rowptr = deg + NN;                         // NN+1
    int* cursor = rowptr + NN + 1;                  // NN
    int* bsum = cursor + NN;                        // SCAN_NB
    int* colsorted = bsum + SCAN_NB;                // NE

    const int eb = (NE + 255) / 256;
    const int nb = (NN + 255) / 256;
    const int gb = (NN * 32 + 255) / 256;           // 12500
    const int ub = (NV4 + 255) / 256;               // 3125

    zero_deg_kernel<<<nb, 256, 0, stream>>>(deg);
    hist_kernel<<<eb, 256, 0, stream>>>(row, deg);
    blocksum_kernel<<<SCAN_NB, 256, 0, stream>>>(deg, bsum);
    scanbsum_kernel<<<1, 128, 0, stream>>>(bsum);
    scanfinal_kernel<<<SCAN_NB, 256, 0, stream>>>(deg, bsum, rowptr, cursor);
    fill_kernel<<<eb, 256, 0, stream>>>(row, col, cursor, colsorted);

    for (int it = 0; it < KIT; ++it) {
        const float* cur = (it == 0) ? h_in : out;
        agg_kernel<<<gb, 256, 0, stream>>>(cur, rowptr, colsorted, S,
                                           maxslots + it * NSLOT);
        update_kernel<<<ub, 256, 0, stream>>>((const float4*)cur, (float4*)out,
                                              (const float4*)S,
                                              maxslots + it * NSLOT);
    }
}

// Round 6
// 640.979 us; speedup vs baseline: 19.5485x; 1.0463x over previous
//
#include <hip/hip_runtime.h>

#define NN 100000
#define NE 1600000
#define DF 32
#define KIT 5
#define MU 0.01f
#define NSLOT 256
#define NV4 (NN * DF / 4)

#define SCAN_CHUNK 1024
#define SCAN_NB ((NN + SCAN_CHUNK - 1) / SCAN_CHUNK)  // 98 blocks

// ---------- one-time CSR build (row is iteration-invariant) ----------

__global__ __launch_bounds__(256) void zero_deg_kernel(int* __restrict__ deg) {
    int i = blockIdx.x * blockDim.x + threadIdx.x;
    if (i < NN) deg[i] = 0;
}

__global__ __launch_bounds__(256) void hist_kernel(const int* __restrict__ row,
                                                   int* __restrict__ deg) {
    int e = blockIdx.x * blockDim.x + threadIdx.x;
    if (e < NE) atomicAdd(&deg[row[e]], 1);
}

__global__ __launch_bounds__(256) void blocksum_kernel(const int* __restrict__ deg,
                                                       int* __restrict__ bsum) {
    const int t = threadIdx.x;
    const int base = blockIdx.x * SCAN_CHUNK + t * 4;
    int s = 0;
    #pragma unroll
    for (int i = 0; i < 4; ++i) {
        int idx = base + i;
        if (idx < NN) s += deg[idx];
    }
    #pragma unroll
    for (int m = 32; m > 0; m >>= 1) s += __shfl_xor(s, m, 64);
    __shared__ int sm[4];
    if ((t & 63) == 0) sm[t >> 6] = s;
    __syncthreads();
    if (t == 0) bsum[blockIdx.x] = sm[0] + sm[1] + sm[2] + sm[3];
}

__global__ __launch_bounds__(128) void scanbsum_kernel(int* __restrict__ bsum) {
    __shared__ int sh[SCAN_NB];
    const int t = threadIdx.x;
    if (t < SCAN_NB) sh[t] = bsum[t];
    __syncthreads();
    if (t == 0) {
        int run = 0;
        for (int i = 0; i < SCAN_NB; ++i) {
            int v = sh[i];
            sh[i] = run;
            run += v;
        }
    }
    __syncthreads();
    if (t < SCAN_NB) bsum[t] = sh[t];
}

__global__ __launch_bounds__(256) void scanfinal_kernel(const int* __restrict__ deg,
                                                        const int* __restrict__ bsum,
                                                        int* __restrict__ rowptr,
                                                        int* __restrict__ cursor) {
    const int t = threadIdx.x;
    const int base = blockIdx.x * SCAN_CHUNK + t * 4;
    int d[4];
    int s = 0;
    #pragma unroll
    for (int i = 0; i < 4; ++i) {
        int idx = base + i;
        d[i] = (idx < NN) ? deg[idx] : 0;
        s += d[i];
    }
    __shared__ int sh[256];
    sh[t] = s;
    __syncthreads();
    for (int off = 1; off < 256; off <<= 1) {
        int v = (t >= off) ? sh[t - off] : 0;
        __syncthreads();
        sh[t] += v;
        __syncthreads();
    }
    int run = bsum[blockIdx.x] + sh[t] - s;
    #pragma unroll
    for (int i = 0; i < 4; ++i) {
        int idx = base + i;
        if (idx < NN) {
            rowptr[idx] = run;
            cursor[idx] = run;
            run += d[i];
        }
    }
    if (blockIdx.x == 0 && t == 0) rowptr[NN] = NE;
}

__global__ __launch_bounds__(256) void fill_kernel(const int* __restrict__ row,
                                                   const int* __restrict__ col,
                                                   int* __restrict__ cursor,
                                                   int* __restrict__ colsorted) {
    int e = blockIdx.x * blockDim.x + threadIdx.x;
    if (e < NE) {
        int pos = atomicAdd(&cursor[row[e]], 1);
        colsorted[pos] = col[e];
    }
}

// ---------- per-iteration ----------

// One 32-lane group per node. lane = oct(2b)*8 + fl(3b).
// Each lane loads float4 (features fl*4..+3); an octet (8 lanes) covers one
// 128B neighbor row, so the group gathers 4 rows per load instruction.
// Per-edge norm: 3 shuffles (xor 1,2,4 within octet). Unroll 2 quads = 8
// edges in flight. Tail edges gather the node's own row -> d=0 (no effect on
// acc; norm clamps to 1e-6 which never changes the max).
__global__ __launch_bounds__(256) void agg_kernel(const float* __restrict__ h,
                                                  const int* __restrict__ rowptr,
                                                  const int* __restrict__ colsorted,
                                                  float* __restrict__ S,
                                                  int* __restrict__ maxslots) {
    const int lane = threadIdx.x & 31;
    const int oct = lane >> 3;
    const int fl = lane & 7;
    const int node = (blockIdx.x * blockDim.x + threadIdx.x) >> 5;

    const float4 hr4 = ((const float4*)h)[node * 8 + fl];
    const int start = rowptr[node];
    const int end = rowptr[node + 1];

    float4 acc = make_float4(0.f, 0.f, 0.f, 0.f);
    float nmax = 0.0f;

    for (int k = start; k < end; k += 8) {
        const int e0 = k + oct;
        const int e1 = k + 4 + oct;
        const int c0 = (e0 < end) ? colsorted[e0] : node;
        const int c1 = (e1 < end) ? colsorted[e1] : node;
        const float4 hc0 = ((const float4*)h)[c0 * 8 + fl];
        const float4 hc1 = ((const float4*)h)[c1 * 8 + fl];

        const float dx0 = hr4.x - hc0.x, dy0 = hr4.y - hc0.y,
                    dz0 = hr4.z - hc0.z, dw0 = hr4.w - hc0.w;
        const float dx1 = hr4.x - hc1.x, dy1 = hr4.y - hc1.y,
                    dz1 = hr4.z - hc1.z, dw1 = hr4.w - hc1.w;
        float s0 = dx0 * dx0 + dy0 * dy0 + dz0 * dz0 + dw0 * dw0;
        float s1 = dx1 * dx1 + dy1 * dy1 + dz1 * dz1 + dw1 * dw1;
        #pragma unroll
        for (int m = 1; m < 8; m <<= 1) {
            s0 += __shfl_xor(s0, m, 32);
            s1 += __shfl_xor(s1, m, 32);
        }
        const float n0 = fmaxf(sqrtf(s0), 1e-6f);
        const float n1 = fmaxf(sqrtf(s1), 1e-6f);
        nmax = fmaxf(nmax, fmaxf(n0, n1));
        const float w0 = rsqrtf(n0);
        const float w1 = rsqrtf(n1);
        acc.x -= dx0 * w0 + dx1 * w1;
        acc.y -= dy0 * w0 + dy1 * w1;
        acc.z -= dz0 * w0 + dz1 * w1;
        acc.w -= dw0 * w0 + dw1 * w1;
    }

    // cross-octet reduce of acc (features align across octets)
    #pragma unroll
    for (int m = 8; m < 32; m <<= 1) {
        acc.x += __shfl_xor(acc.x, m, 32);
        acc.y += __shfl_xor(acc.y, m, 32);
        acc.z += __shfl_xor(acc.z, m, 32);
        acc.w += __shfl_xor(acc.w, m, 32);
    }
    if (oct == 0) ((float4*)S)[node * 8 + fl] = acc;

    // group max -> wave max -> spread atomic
    nmax = fmaxf(nmax, __shfl_xor(nmax, 8, 32));
    nmax = fmaxf(nmax, __shfl_xor(nmax, 16, 32));
    nmax = fmaxf(nmax, __shfl_xor(nmax, 32, 64));
    if ((threadIdx.x & 63) == 0) {
        // positive floats order like ints; 0xAA poison is negative -> loses
        atomicMax(&maxslots[blockIdx.x & (NSLOT - 1)], __float_as_int(nmax));
    }
}

// h_out = h_in - MU*sqrt(M)*S   (elementwise; in-place safe)
__global__ __launch_bounds__(256) void update_kernel(const float4* __restrict__ hcur,
                                                     float4* __restrict__ hnxt,
                                                     const float4* __restrict__ S,
                                                     const int* __restrict__ slots) {
    const int t = threadIdx.x;
    int v = slots[t];
    #pragma unroll
    for (int m = 32; m > 0; m >>= 1) v = max(v, __shfl_xor(v, m, 64));
    __shared__ int sm[4];
    __shared__ float sscale;
    if ((t & 63) == 0) sm[t >> 6] = v;
    __syncthreads();
    if (t == 0) {
        int bm = max(max(sm[0], sm[1]), max(sm[2], sm[3]));
        sscale = MU * sqrtf(__int_as_float(bm));
    }
    __syncthreads();
    const float scale = sscale;
    const int i = blockIdx.x * blockDim.x + t;
    if (i < NV4) {
        const float4 hv = hcur[i];
        const float4 sv = S[i];
        float4 o;
        o.x = hv.x - scale * sv.x;
        o.y = hv.y - scale * sv.y;
        o.z = hv.z - scale * sv.z;
        o.w = hv.w - scale * sv.w;
        hnxt[i] = o;
    }
}

extern "C" void kernel_launch(void* const* d_in, const int* in_sizes, int n_in,
                              void* d_out, int out_size, void* d_ws, size_t ws_size,
                              hipStream_t stream) {
    const float* h_in = (const float*)d_in[0];
    const int* row = (const int*)d_in[1];
    const int* col = row + NE;
    float* out = (float*)d_out;

    float* S = (float*)d_ws;                        // NN*DF f32
    int* maxslots = (int*)(S + NN * DF);            // KIT*NSLOT
    int* deg = maxslots + KIT * NSLOT;              // NN
    int* rowptr = deg + NN;                         // NN+1
    int* cursor = rowptr + NN + 1;                  // NN
    int* bsum = cursor + NN;                        // SCAN_NB
    int* colsorted = bsum + SCAN_NB;                // NE

    const int eb = (NE + 255) / 256;
    const int nb = (NN + 255) / 256;
    const int gb = (NN * 32 + 255) / 256;           // 12500
    const int ub = (NV4 + 255) / 256;               // 3125

    zero_deg_kernel<<<nb, 256, 0, stream>>>(deg);
    hist_kernel<<<eb, 256, 0, stream>>>(row, deg);
    blocksum_kernel<<<SCAN_NB, 256, 0, stream>>>(deg, bsum);
    scanbsum_kernel<<<1, 128, 0, stream>>>(bsum);
    scanfinal_kernel<<<SCAN_NB, 256, 0, stream>>>(deg, bsum, rowptr, cursor);
    fill_kernel<<<eb, 256, 0, stream>>>(row, col, cursor, colsorted);

    for (int it = 0; it < KIT; ++it) {
        const float* cur = (it == 0) ? h_in : out;
        agg_kernel<<<gb, 256, 0, stream>>>(cur, rowptr, colsorted, S,
                                           maxslots + it * NSLOT);
        update_kernel<<<ub, 256, 0, stream>>>((const float4*)cur, (float4*)out,
                                              (const float4*)S,
                                              maxslots + it * NSLOT);
    }
}